// Round 12
// baseline (650.238 us; speedup 1.0000x reference)
//
#include <hip/hip_runtime.h>
#include <math.h>

// FineMatching fused kernel, MI355X (gfx950).
// One block per m (M=8192). 256 threads = 4 waves; lane = l (0..63),
// wave wv owns r-chunk [wv*25, wv*25+25).
//
// sm = softmax_l(conf) * softmax_r(conf) = e^2 / (rowsum * colsum),
// e = exp(conf); no max subtraction needed (|conf| <= ~0.5, f32 safe).
// expf() (ocml, ~1ulp) not __expf(): sm is near-flat, argmax vs the f32
// reference is sensitive to ~1e-6 perturbations.
//
// B-operand (f1 rows): row address is wave-uniform (readfirstlane'd) ->
// ideally lowered to s_load_dwordx4/x8/x16 (SMEM pipe, LDS stays empty,
// no staging barrier). Loads are float4-wide so the worst-case fallback
// is 350 broadcast global_load_dwordx4 (L1-hit) per wave, not 1400
// scalar loads.
//
// Column sums go through an LDS transpose (esh) on purpose: the
// __shfl_xor butterfly alternative costs 600 LDS-pipe wave-instrs/block
// (ds_swizzle lowering) vs 228 for this path — rejected on paper.

constexpr int EPAD = 101;  // e-matrix stride: (5*lane+r)%32 -> 2-way, free
constexpr int SPAD = 65;   // sm-center stride: odd -> 2-way on stores, free

typedef float fvec4 __attribute__((ext_vector_type(4)));  // Clang vector:
// HIP float4 is a class type; __builtin_nontemporal_store needs this.

__global__ void __launch_bounds__(256, 4)
fm_kernel(const float* __restrict__ feat0,
          const float* __restrict__ feat1,
          const float* __restrict__ mk0,
          const float* __restrict__ mk1,
          float* __restrict__ out)
{
  const int m    = blockIdx.x;
  const int tid  = threadIdx.x;
  const int lane = tid & 63;
  const int wv   = tid >> 6;
  const int M    = gridDim.x;

  // 25.9 KB aliased buffer, lifetimes separated by barriers:
  //   phase A: esh[64*101]   (e matrix, for column sums)
  //   phase B: smc[64*65]    (center 8x8 staging)
  __shared__ float big[6464];
  float* esh = big;
  float* smc = big;
  __shared__ float prs[256];     // per-(wave,lane) row-sum partials
  __shared__ float rsinv[64];
  __shared__ float csinv[100];
  __shared__ float amv[256];
  __shared__ int   ami[256];

  const float* f0g = feat0 + (size_t)m * 4096;
  const float* f1g = feat1 + (size_t)m * 6400;

  // ---------------- f0 row (l = lane) -> registers ---------------------
  // 14 x dwordx4 at 256B lane stride; 4 consecutive k reuse each 64B line.
  float a[56];
  #pragma unroll
  for (int k = 0; k < 14; ++k) {
    float4 v = *(const float4*)(f0g + lane * 64 + k * 4);
    a[k * 4 + 0] = v.x; a[k * 4 + 1] = v.y;
    a[k * 4 + 2] = v.z; a[k * 4 + 3] = v.w;
  }

  // ---------------- conf GEMM + fused exp (B rows uniform) -------------
  const int r0 = __builtin_amdgcn_readfirstlane(wv) * 25;  // SGPR row base
  const float* f1w = f1g + r0 * 64;

  float e[25];
  float rsum = 0.f;
  #pragma unroll
  for (int i = 0; i < 25; ++i) {
    const float4* fr = (const float4*)(f1w + i * 64);  // wave-uniform addr
    float acc = 0.f;
    #pragma unroll
    for (int c4 = 0; c4 < 14; ++c4) {
      float4 b = fr[c4];
      acc = fmaf(a[c4 * 4 + 0], b.x, acc);
      acc = fmaf(a[c4 * 4 + 1], b.y, acc);
      acc = fmaf(a[c4 * 4 + 2], b.z, acc);
      acc = fmaf(a[c4 * 4 + 3], b.w, acc);
    }
    e[i] = expf(acc * 0.015625f);   // conf = acc/64 (1/sqrt(C) per operand)
    rsum += e[i];
  }

  prs[tid] = rsum;
  #pragma unroll
  for (int i = 0; i < 25; ++i) esh[lane * EPAD + r0 + i] = e[i];
  __syncthreads();

  // ---------------- column sums (waves 0-1), row sums (wave 2) ---------
  if (wv < 2) {
    int r = wv * 64 + lane;
    if (r < 100) {
      float s0 = 0.f, s1 = 0.f, s2 = 0.f, s3 = 0.f;
      #pragma unroll
      for (int l = 0; l < 64; l += 4) {       // conflict-free (stride 101)
        s0 += esh[(l + 0) * EPAD + r];
        s1 += esh[(l + 1) * EPAD + r];
        s2 += esh[(l + 2) * EPAD + r];
        s3 += esh[(l + 3) * EPAD + r];
      }
      csinv[r] = 1.0f / ((s0 + s1) + (s2 + s3));
    }
  } else if (wv == 2) {
    float rs = prs[lane] + prs[lane + 64] + prs[lane + 128] + prs[lane + 192];
    rsinv[lane] = 1.0f / rs;
  }
  __syncthreads();

  // ---------------- sm, argmax, stage center 8x8 -----------------------
  float best = -1.0e30f;
  int   bidx = 0x7fffffff;
  {
    float ri = rsinv[lane];
    #pragma unroll
    for (int i = 0; i < 25; ++i) {
      int r = r0 + i;
      int p = r / 10, q = r - p * 10;          // wave-uniform (SALU)
      if (p >= 1 && p <= 8 && q >= 1 && q <= 8) {
        float sv = e[i] * e[i] * ri * csinv[r];
        int j = (p - 1) * 8 + (q - 1);
        smc[lane * SPAD + j] = sv;
        if (sv > best) { best = sv; bidx = lane * 64 + j; }  // j ascending ->
      }                                                       // first-max kept
    }
  }
  amv[tid] = best; ami[tid] = bidx;
  __syncthreads();

  // ---------------- final argmax (wave 0; tid0 keeps ix in-register) ---
  int ix_final = 0;
  if (wv == 0) {
    float v = amv[lane]; int ix = ami[lane];
    #pragma unroll
    for (int k = 64; k < 256; k += 64) {
      float v2 = amv[k + lane]; int i2 = ami[k + lane];
      if (v2 > v || (v2 == v && i2 < ix)) { v = v2; ix = i2; }
    }
    #pragma unroll
    for (int s = 32; s > 0; s >>= 1) {
      float v2 = __shfl_xor(v, s);
      int   i2 = __shfl_xor(ix, s);
      if (v2 > v || (v2 == v && i2 < ix)) { v = v2; ix = i2; }
    }
    ix_final = ix;
  }

  // -------- flush sm center to global (coalesced, streaming nt) --------
  float* outm = out + (size_t)m * 4096;
  #pragma unroll
  for (int k = 0; k < 4; ++k) {
    int d = k * 1024 + tid * 4;
    int row = d >> 6, col = d & 63;
    fvec4 v;                                    // b32 gather: 2 lanes/bank
    v.x = smc[row * SPAD + col + 0];
    v.y = smc[row * SPAD + col + 1];
    v.z = smc[row * SPAD + col + 2];
    v.w = smc[row * SPAD + col + 3];
    __builtin_nontemporal_store(v, (fvec4*)(outm + d));    // never re-read
  }

  // ---------------- fine phase (thread 0, hidden under flush) ----------
  if (tid == 0) {
    int ix = ix_final;
    int il = ix >> 6, irr = ix & 63;
    int ir = irr >> 3, jr = irr & 7;

    float p0[8];
    const float* ff0 = f0g + il * 64 + 56;          // ff0 row, unscaled
    #pragma unroll
    for (int c = 0; c < 8; ++c) p0[c] = ff0[c];

    float win[9];
    #pragma unroll
    for (int ab = 0; ab < 9; ++ab) {
      int aa = ab / 3, bb = ab - aa * 3;
      // win[u][v] = conf_ff[il][(ir+v)*10 + (jr+u)], ab = u*3+v
      const float* qq = f1g + ((ir + bb) * 10 + (jr + aa)) * 64 + 56;
      float s = 0.f;
      #pragma unroll
      for (int c = 0; c < 8; ++c) s = fmaf(p0[c], qq[c], s);
      win[ab] = s * 0.3535533905932738f;            // 1/sqrt(8)
    }
    float mx = win[0];
    #pragma unroll
    for (int ab = 1; ab < 9; ++ab) mx = fmaxf(mx, win[ab]);
    float h[9], hs = 0.f;
    #pragma unroll
    for (int ab = 0; ab < 9; ++ab) { h[ab] = expf((win[ab] - mx) * 0.1f); hs += h[ab]; }
    float ih = 1.0f / hs;

    // 3x3 ones conv, zero padding; then normalized centroid
    float cc[9], csum = 0.f;
    #pragma unroll
    for (int i = 0; i < 3; ++i) {
      #pragma unroll
      for (int j = 0; j < 3; ++j) {
        float s = 0.f;
        #pragma unroll
        for (int u = 0; u < 3; ++u) {
          #pragma unroll
          for (int v = 0; v < 3; ++v) {
            int ui = i - 1 + u, vj = j - 1 + v;
            if (ui >= 0 && ui < 3 && vj >= 0 && vj < 3) s += h[ui * 3 + vj] * ih;
          }
        }
        cc[i * 3 + j] = s; csum += s;
      }
    }
    float ic = 1.0f / csum;
    float cx = 0.f, cy = 0.f;
    #pragma unroll
    for (int i = 0; i < 3; ++i) {
      #pragma unroll
      for (int j = 0; j < 3; ++j) { cx += cc[i * 3 + j] * ic * j; cy += cc[i * 3 + j] * ic * i; }
    }
    cx -= 1.0f; cy -= 1.0f;

    float* omk0 = out + (size_t)M * 4096;
    float* omk1 = omk0 + (size_t)M * 2;
    omk0[m * 2 + 0] = mk0[m * 2 + 0] + ((float)(il >> 3) - 3.5f) * 2.0f;
    omk0[m * 2 + 1] = mk0[m * 2 + 1] + ((float)(il & 7)  - 3.5f) * 2.0f;
    omk1[m * 2 + 0] = mk1[m * 2 + 0] + ((float)ir - 3.5f + cx) * 2.0f;
    omk1[m * 2 + 1] = mk1[m * 2 + 1] + ((float)jr - 3.5f + cy) * 2.0f;
  }
}

extern "C" void kernel_launch(void* const* d_in, const int* in_sizes, int n_in,
                              void* d_out, int out_size, void* d_ws, size_t ws_size,
                              hipStream_t stream) {
  const float* feat0 = (const float*)d_in[0];
  const float* feat1 = (const float*)d_in[1];
  const float* mk0   = (const float*)d_in[2];
  const float* mk1   = (const float*)d_in[3];
  const int M = in_sizes[2] / 2;           // mkpts0_c is (M,2)
  fm_kernel<<<dim3(M), dim3(256), 0, stream>>>(feat0, feat1, mk0, mk1, (float*)d_out);
}